// Round 2
// baseline (1395.269 us; speedup 1.0000x reference)
//
#include <hip/hip_runtime.h>
#include <cstdint>
#include <cstddef>

#define TT 256
#define NN 4096
#define CC 12
#define DD 256
#define KD 12
#define NB 16
#define NTH 512
#define HS 264   // halfs per h row: 256 + 8 pad (rows 16B-aligned)
#define XS 40    // halfs per x row: 32 + 8 pad
#define YS 20    // floats per yred row: 16 + 4 pad (rows 16B-aligned, conflict-free)

typedef _Float16 half8 __attribute__((ext_vector_type(8)));
typedef float f32x4 __attribute__((ext_vector_type(4)));
#define MFMA __builtin_amdgcn_mfma_f32_16x16x32_f16

struct FalseC { static constexpr bool value = false; };
struct TrueC  { static constexpr bool value = true;  };

// LDS: 33,792 (h planes) + 10,240 (4 x slots) + 3,840 (yred x3) = 47,872 B
struct alignas(16) SM {
  _Float16 hhi[2][NB][HS];   // h hi plane, double-buffered
  _Float16 hlo[2][NB][HS];   // h lo plane
  _Float16 xhi[4][NB][XS];   // x_t slots (4-deep for distance-2 prefetch)
  _Float16 xlo[4][NB][XS];
  float    yred[3][NB][YS];  // decoder y accumulator, triple-buffered
};

__device__ __forceinline__ void split8(const float* w, half8& hi, half8& lo) {
  #pragma unroll
  for (int j = 0; j < 8; ++j) {
    _Float16 h = (_Float16)w[j];
    hi[j] = h;
    lo[j] = (_Float16)(w[j] - (float)h);
  }
}

__device__ __forceinline__ unsigned pack2(_Float16 a, _Float16 b) {
  union { _Float16 h[2]; unsigned u; } x;
  x.h[0] = a; x.h[1] = b;
  return x.u;
}

// Raw barrier: drain LDS, sync. Single asm block = compiler memory fence on
// both sides (loads can't hoist above, stores can't sink below), but NO
// sched_barrier -> address math and prefetch scheduling can pipeline across
// steps, and in-flight global ops (x prefetch, out stores) are never drained.
__device__ __forceinline__ void BAR() {
  asm volatile("s_waitcnt lgkmcnt(0)\n\ts_barrier" ::: "memory");
}

__global__ __launch_bounds__(NTH, 2)
void seq2seq_kernel(const float* __restrict__ x,
                    const float* __restrict__ enc_Wx,
                    const float* __restrict__ enc_bx,
                    const float* __restrict__ enc_Wh,
                    const float* __restrict__ dec_Wx,
                    const float* __restrict__ dec_bx,
                    const float* __restrict__ dec_Wh,
                    const float* __restrict__ dec_Wy,
                    const float* __restrict__ dec_by,
                    float* __restrict__ out)
{
  __shared__ SM sm;
  const int tid  = (int)threadIdx.x;
  const int wid  = tid >> 6;
  const int lane = tid & 63;
  const int l15  = lane & 15;
  const int quad = lane >> 4;
  const int n0   = (int)blockIdx.x * NB;

  half8 Whi[2][8], Wlo[2][8];   // Wh B-fragments (reg-resident), persistent
  half8 Xhi[2], Xlo[2];         // Wx B-fragments (K=32 padded chunk)
  float bxr[2];
  // two prefetch register sets (x_{t+2} issued at step t, written at end of t+1)
  float pfA0 = 0.f, pfA1 = 0.f, pfA2 = 0.f;
  float pfB0 = 0.f, pfB1 = 0.f, pfB2 = 0.f;

  // earliest possible issue of x_1 (consumed at end of encoder step 0)
  if (wid == 1) {
    const float* xg = x + ((size_t)1 * NN + n0) * CC;
    pfB0 = xg[lane]; pfB1 = xg[lane + 64]; pfB2 = xg[lane + 128];
  }

  // B column mapping: n = wid*32 + 2*l15 + tt  (lane's two outputs ADJACENT ->
  // packed b32 h-writes, zero write bank conflicts: quads hit disjoint 16-bank
  // halves, 2 lanes/bank = free)
  auto loadWh = [&](const float* __restrict__ W) {
    #pragma unroll
    for (int tt = 0; tt < 2; ++tt) {
      const int n = wid * 32 + 2 * l15 + tt;
      #pragma unroll
      for (int c = 0; c < 8; ++c) {
        float w[8];
        const float* p = W + (size_t)n * DD + c * 32 + quad * 8;
        *(float4*)&w[0] = *(const float4*)p;
        *(float4*)&w[4] = *(const float4*)(p + 4);
        split8(w, Whi[tt][c], Wlo[tt][c]);
      }
    }
  };
  auto loadWx = [&](const float* __restrict__ Wx) {
    #pragma unroll
    for (int tt = 0; tt < 2; ++tt) {
      const int n = wid * 32 + 2 * l15 + tt;
      float w[8];
      #pragma unroll
      for (int j = 0; j < 8; ++j) {
        const int k = quad * 8 + j;
        w[j] = (k < CC) ? Wx[(size_t)n * CC + k] : 0.f;
      }
      split8(w, Xhi[tt], Xlo[tt]);
    }
  };
  auto loadBx = [&](const float* __restrict__ bx) {
    #pragma unroll
    for (int tt = 0; tt < 2; ++tt) bxr[tt] = bx[wid * 32 + 2 * l15 + tt];
  };

  // ---------------- init ----------------
  {
    unsigned* z;
    z = (unsigned*)&sm.hhi[0][0][0];
    for (int i = tid; i < NB * HS / 2; i += NTH) z[i] = 0u;
    z = (unsigned*)&sm.hlo[0][0][0];
    for (int i = tid; i < NB * HS / 2; i += NTH) z[i] = 0u;
    z = (unsigned*)&sm.xhi[0][0][0];
    for (int i = tid; i < 4 * NB * XS / 2; i += NTH) z[i] = 0u;
    z = (unsigned*)&sm.xlo[0][0][0];
    for (int i = tid; i < 4 * NB * XS / 2; i += NTH) z[i] = 0u;
  }
  loadWh(enc_Wh);
  loadWx(enc_Wx);
  loadBx(enc_bx);
  BAR();
  if (tid < NB * CC) {  // stage x_0 into slot 0
    const float v = x[(size_t)n0 * CC + tid];
    const _Float16 h = (_Float16)v;
    sm.xhi[0][tid / CC][tid % CC] = h;
    sm.xlo[0][tid / CC][tid % CC] = (_Float16)(v - (float)h);
  }
  BAR();

  // ---------------- encoder: 1 raw barrier/step, distance-2 prefetch ----------------
  auto encStep = [&](int t, auto IAc) {
    constexpr bool IA = decltype(IAc)::value;
    if (wid == 1) {  // issue x_{t+2} into set A (even t) / set B (odd t)
      const int tp = (t + 2 < TT) ? (t + 2) : (TT - 1);
      const float* xg = x + ((size_t)tp * NN + n0) * CC;
      if constexpr (IA) { pfA0 = xg[lane]; pfA1 = xg[lane + 64]; pfA2 = xg[lane + 128]; }
      else              { pfB0 = xg[lane]; pfB1 = xg[lane + 64]; pfB2 = xg[lane + 128]; }
    }
    const int rb = t & 1, wb = rb ^ 1, xs = t & 3;
    f32x4 aA0 = {0.f,0.f,0.f,0.f}, aA1 = {0.f,0.f,0.f,0.f};
    f32x4 aB0 = {0.f,0.f,0.f,0.f}, aB1 = {0.f,0.f,0.f,0.f};
    // x-term first: fills MFMA pipe while h reads stream in
    const half8 xh = *(const half8*)&sm.xhi[xs][l15][quad * 8];
    const half8 xl = *(const half8*)&sm.xlo[xs][l15][quad * 8];
    aA0 = MFMA(xh, Xhi[0], aA0, 0, 0, 0);
    aA1 = MFMA(xh, Xhi[1], aA1, 0, 0, 0);
    aB0 = MFMA(xl, Xhi[0], aB0, 0, 0, 0);
    aB1 = MFMA(xl, Xhi[1], aB1, 0, 0, 0);
    aB0 = MFMA(xh, Xlo[0], aB0, 0, 0, 0);
    aB1 = MFMA(xh, Xlo[1], aB1, 0, 0, 0);
    const _Float16* hh = &sm.hhi[rb][l15][0];
    const _Float16* hl = &sm.hlo[rb][l15][0];
    #pragma unroll
    for (int c = 0; c < 8; ++c) {
      const half8 ahi = *(const half8*)(hh + c * 32 + quad * 8);
      const half8 alo = *(const half8*)(hl + c * 32 + quad * 8);
      aA0 = MFMA(ahi, Whi[0][c], aA0, 0, 0, 0);
      aA1 = MFMA(ahi, Whi[1][c], aA1, 0, 0, 0);
      aB0 = MFMA(alo, Whi[0][c], aB0, 0, 0, 0);
      aB1 = MFMA(alo, Whi[1][c], aB1, 0, 0, 0);
      aA0 = MFMA(ahi, Wlo[0][c], aA0, 0, 0, 0);
      aA1 = MFMA(ahi, Wlo[1][c], aA1, 0, 0, 0);
    }
    const int colh = wid * 32 + 2 * l15;
    #pragma unroll
    for (int r = 0; r < 4; ++r) {
      const int m = quad * 4 + r;
      const float v0 = fmaxf(aA0[r] + aB0[r] + bxr[0], 0.f);
      const float v1 = fmaxf(aA1[r] + aB1[r] + bxr[1], 0.f);
      const _Float16 h0 = (_Float16)v0, h1 = (_Float16)v1;
      *(unsigned*)&sm.hhi[wb][m][colh] = pack2(h0, h1);
      *(unsigned*)&sm.hlo[wb][m][colh] =
          pack2((_Float16)(v0 - (float)h0), (_Float16)(v1 - (float)h1));
    }
    if (wid == 1) {  // write x_{t+1} (the OTHER set, issued one step ago)
      const int xw = (t + 1) & 3;
      float w0, w1, w2;
      if constexpr (IA) { w0 = pfB0; w1 = pfB1; w2 = pfB2; }
      else              { w0 = pfA0; w1 = pfA1; w2 = pfA2; }
      #pragma unroll
      for (int j = 0; j < 3; ++j) {
        const int i = lane + 64 * j;
        const float vv = (j == 0) ? w0 : (j == 1) ? w1 : w2;
        const _Float16 hx = (_Float16)vv;
        sm.xhi[xw][i / CC][i % CC] = hx;
        sm.xlo[xw][i / CC][i % CC] = (_Float16)(vv - (float)hx);
      }
    }
    BAR();
  };

  for (int t = 0; t < TT; t += 2) {
    encStep(t, TrueC{});
    encStep(t + 1, FalseC{});
  }
  // encoder final h now in planes[0]

  // ---------------- decoder setup ----------------
  loadWh(dec_Wh);
  loadWx(dec_Wx);
  loadBx(dec_bx);
  float by4[4];
  #pragma unroll
  for (int j = 0; j < 4; ++j) {
    const int o = quad * 4 + j;
    by4[j] = (o < KD) ? dec_by[o] : 0.f;
  }
  half8 wyh, wyl;  // dec_Wy B-fragment for THIS wave's k-chunk (registers)
  {
    float w[8];
    if (l15 < KD) {
      const float* p = dec_Wy + (size_t)l15 * DD + wid * 32 + quad * 8;
      *(float4*)&w[0] = *(const float4*)p;
      *(float4*)&w[4] = *(const float4*)(p + 4);
    } else {
      #pragma unroll
      for (int j = 0; j < 8; ++j) w[j] = 0.f;
    }
    split8(w, wyh, wyl);
  }
  // sos one-hot A-fragment in registers: column CC-2 = 10
  half8 aX;
  #pragma unroll
  for (int j = 0; j < 8; ++j)
    aX[j] = (_Float16)((quad * 8 + j == CC - 2) ? 1.f : 0.f);
  {  // zero all three yred buffers
    float* zp = &sm.yred[0][0][0];
    for (int i = tid; i < 3 * NB * YS; i += NTH) zp[i] = 0.f;
  }
  BAR();

  // ---------------- decoder: ONE raw barrier/step ----------------
  for (int t = 0; t < TT; ++t) {
    const int rb = t & 1, wb = rb ^ 1;
    const int yb = t % 3, zb = (t + 2) % 3;
    f32x4 aA0 = {0.f,0.f,0.f,0.f}, aA1 = {0.f,0.f,0.f,0.f};
    f32x4 aB0 = {0.f,0.f,0.f,0.f}, aB1 = {0.f,0.f,0.f,0.f};
    // x-term from in-register one-hot sos (exact in f16 -> no lo A plane)
    aA0 = MFMA(aX, Xhi[0], aA0, 0, 0, 0);
    aA1 = MFMA(aX, Xhi[1], aA1, 0, 0, 0);
    aB0 = MFMA(aX, Xlo[0], aB0, 0, 0, 0);
    aB1 = MFMA(aX, Xlo[1], aB1, 0, 0, 0);
    const _Float16* hh = &sm.hhi[rb][l15][0];
    const _Float16* hl = &sm.hlo[rb][l15][0];
    #pragma unroll
    for (int c = 0; c < 8; ++c) {
      const half8 ahi = *(const half8*)(hh + c * 32 + quad * 8);
      const half8 alo = *(const half8*)(hl + c * 32 + quad * 8);
      aA0 = MFMA(ahi, Whi[0][c], aA0, 0, 0, 0);
      aA1 = MFMA(ahi, Whi[1][c], aA1, 0, 0, 0);
      aB0 = MFMA(alo, Whi[0][c], aB0, 0, 0, 0);
      aB1 = MFMA(alo, Whi[1][c], aB1, 0, 0, 0);
      aA0 = MFMA(ahi, Wlo[0][c], aA0, 0, 0, 0);
      aA1 = MFMA(ahi, Wlo[1][c], aA1, 0, 0, 0);
    }
    const int colh = wid * 32 + 2 * l15;
    #pragma unroll
    for (int r = 0; r < 4; ++r) {
      const int m = quad * 4 + r;
      const float v0 = fmaxf(aA0[r] + aB0[r] + bxr[0], 0.f);
      const float v1 = fmaxf(aA1[r] + aB1[r] + bxr[1], 0.f);
      const _Float16 h0 = (_Float16)v0, h1 = (_Float16)v1;
      *(unsigned*)&sm.hhi[wb][m][colh] = pack2(h0, h1);
      *(unsigned*)&sm.hlo[wb][m][colh] =
          pack2((_Float16)(v0 - (float)h0), (_Float16)(v1 - (float)h1));
    }
    // y-partial from OWN just-written 32-col slice (no cross-wave dependency)
    asm volatile("s_waitcnt lgkmcnt(0)" ::: "memory");  // own writes -> readable
    const half8 yh8 = *(const half8*)&sm.hhi[wb][l15][wid * 32 + quad * 8];
    const half8 yl8 = *(const half8*)&sm.hlo[wb][l15][wid * 32 + quad * 8];
    f32x4 yp = {0.f,0.f,0.f,0.f};
    yp = MFMA(yh8, wyh, yp, 0, 0, 0);
    yp = MFMA(yl8, wyh, yp, 0, 0, 0);
    yp = MFMA(yh8, wyl, yp, 0, 0, 0);
    // accumulate into shared y: yp[r] is partial y[m=quad*4+r][o=l15]
    #pragma unroll
    for (int r = 0; r < 4; ++r)
      atomicAdd(&sm.yred[yb][quad * 4 + r][l15], yp[r]);
    BAR();  // h_t published + y fully accumulated
    // every wave: reduce-read + argmax for row m = l15 (exactly what aX needs)
    const f32x4 y4 = *(const f32x4*)&sm.yred[yb][l15][quad * 4];
    float yv[4];
    #pragma unroll
    for (int j = 0; j < 4; ++j) yv[j] = y4[j] + by4[j];
    if (wid == 0 && quad < 3) {  // single-writer out store, f32x4, fire-and-forget
      float4 st; st.x = yv[0]; st.y = yv[1]; st.z = yv[2]; st.w = yv[3];
      *(float4*)&out[((size_t)t * NN + n0 + l15) * KD + quad * 4] = st;
    }
    // in-lane argmax over this lane's 4 classes (ascending -> first-max kept)
    float v = -1e30f; int io = 0;
    #pragma unroll
    for (int j = 0; j < 4; ++j) {
      const int o = quad * 4 + j;
      const float cv = (o < KD) ? yv[j] : -1e30f;
      const bool take = cv > v;
      io = take ? o : io;
      v  = take ? cv : v;
    }
    // merge across the 4 quads (lane bits 4,5); np first-max tie-break
    #pragma unroll
    for (int d = 16; d < 64; d <<= 1) {
      const float ov = __shfl_xor(v, d);
      const int   oi = __shfl_xor(io, d);
      const bool take = (ov > v) || (ov == v && oi < io);
      v  = take ? ov : v;
      io = take ? oi : io;
    }
    // io = argmax for row l15, present in every lane -> rebuild one-hot A frag
    #pragma unroll
    for (int j = 0; j < 8; ++j)
      aX[j] = (_Float16)((quad * 8 + j == io) ? 1.f : 0.f);
    // zero the buffer for step t+2 (safe: separated from its adds by BAR(t+1))
    {
      float* zp = &sm.yred[zb][0][0];
      if (tid < NB * YS) zp[tid] = 0.f;
    }
  }
}

extern "C" void kernel_launch(void* const* d_in, const int* in_sizes, int n_in,
                              void* d_out, int out_size, void* d_ws, size_t ws_size,
                              hipStream_t stream) {
  (void)in_sizes; (void)n_in; (void)d_ws; (void)ws_size; (void)out_size;
  const float* x      = (const float*)d_in[0];
  const float* enc_Wx = (const float*)d_in[1];
  const float* enc_bx = (const float*)d_in[2];
  const float* enc_Wh = (const float*)d_in[3];
  // d_in[4] enc_Wy, d_in[5] enc_by: computed-but-discarded in the reference
  const float* dec_Wx = (const float*)d_in[6];
  const float* dec_bx = (const float*)d_in[7];
  const float* dec_Wh = (const float*)d_in[8];
  const float* dec_Wy = (const float*)d_in[9];
  const float* dec_by = (const float*)d_in[10];
  float* outp = (float*)d_out;

  seq2seq_kernel<<<NN / NB, NTH, 0, stream>>>(
      x, enc_Wx, enc_bx, enc_Wh, dec_Wx, dec_bx, dec_Wh, dec_Wy, dec_by, outp);
}

// Round 3
// 820.507 us; speedup vs baseline: 1.7005x; 1.7005x over previous
//
#include <hip/hip_runtime.h>
#include <cstdint>
#include <cstddef>

#define TT 256
#define NN 4096
#define CC 12
#define DD 256
#define KD 12
#define NB 16
#define NTH 512
#define HS 264   // halfs per h row: 256 + 8 pad (rows 16B-aligned)
#define XS 40    // halfs per x row: 32 + 8 pad
#define YS 20    // floats per part2 row: 16 + 4 pad (rows 16B-aligned)

typedef _Float16 half8 __attribute__((ext_vector_type(8)));
typedef float f32x4 __attribute__((ext_vector_type(4)));
#define MFMA __builtin_amdgcn_mfma_f32_16x16x32_f16

struct FalseC { static constexpr bool value = false; };
struct TrueC  { static constexpr bool value = true;  };

// LDS: 33,792 (h planes) + 10,240 (4 x slots) + 20,480 (part2 x2) = 64,512 B
struct alignas(16) SM {
  _Float16 hhi[2][NB][HS];    // h hi plane, double-buffered
  _Float16 hlo[2][NB][HS];    // h lo plane
  _Float16 xhi[4][NB][XS];    // x_t slots (4-deep for distance-2 prefetch)
  _Float16 xlo[4][NB][XS];
  float    part2[2][8][NB][YS];  // decoder y partials [buf][wave][row][class]
};

__device__ __forceinline__ void split8(const float* w, half8& hi, half8& lo) {
  #pragma unroll
  for (int j = 0; j < 8; ++j) {
    _Float16 h = (_Float16)w[j];
    hi[j] = h;
    lo[j] = (_Float16)(w[j] - (float)h);
  }
}

__device__ __forceinline__ unsigned pack2(_Float16 a, _Float16 b) {
  union { _Float16 h[2]; unsigned u; } x;
  x.h[0] = a; x.h[1] = b;
  return x.u;
}

// Raw barrier, R1-proven form: drain LDS only (global ops stay in flight),
// builtin convergent s_barrier (backend models it), sched_barrier pins order
// (rule #18: compiler hoists register-only MFMA past bare asm waitcnt).
__device__ __forceinline__ void BAR() {
  asm volatile("s_waitcnt lgkmcnt(0)" ::: "memory");
  __builtin_amdgcn_s_barrier();
  __builtin_amdgcn_sched_barrier(0);
}

__global__ __launch_bounds__(NTH, 2)
void seq2seq_kernel(const float* __restrict__ x,
                    const float* __restrict__ enc_Wx,
                    const float* __restrict__ enc_bx,
                    const float* __restrict__ enc_Wh,
                    const float* __restrict__ dec_Wx,
                    const float* __restrict__ dec_bx,
                    const float* __restrict__ dec_Wh,
                    const float* __restrict__ dec_Wy,
                    const float* __restrict__ dec_by,
                    float* __restrict__ out)
{
  __shared__ SM sm;
  const int tid  = (int)threadIdx.x;
  const int wid  = tid >> 6;
  const int lane = tid & 63;
  const int l15  = lane & 15;
  const int quad = lane >> 4;
  const int n0   = (int)blockIdx.x * NB;

  half8 Whi[2][8], Wlo[2][8];   // Wh B-fragments (reg-resident), persistent
  half8 Xhi[2], Xlo[2];         // Wx B-fragments (K=32 padded chunk)
  float bxr[2];
  // two prefetch register sets (x_{t+2} issued at step t, written at end of t+1)
  float pfA0 = 0.f, pfA1 = 0.f, pfA2 = 0.f;
  float pfB0 = 0.f, pfB1 = 0.f, pfB2 = 0.f;

  // earliest possible issue of x_1 (consumed at end of encoder step 0)
  if (wid == 1) {
    const float* xg = x + ((size_t)1 * NN + n0) * CC;
    pfB0 = xg[lane]; pfB1 = xg[lane + 64]; pfB2 = xg[lane + 128];
  }

  // B column mapping: n = wid*32 + 2*l15 + tt (lane's two outputs ADJACENT ->
  // packed b32 h-writes, 2 lanes/bank = free). LDS layout stays identity
  // (col c holds h[c]); only writer-lane assignment changed.
  auto loadWh = [&](const float* __restrict__ W) {
    #pragma unroll
    for (int tt = 0; tt < 2; ++tt) {
      const int n = wid * 32 + 2 * l15 + tt;
      #pragma unroll
      for (int c = 0; c < 8; ++c) {
        float w[8];
        const float* p = W + (size_t)n * DD + c * 32 + quad * 8;
        *(float4*)&w[0] = *(const float4*)p;
        *(float4*)&w[4] = *(const float4*)(p + 4);
        split8(w, Whi[tt][c], Wlo[tt][c]);
      }
    }
  };
  auto loadWx = [&](const float* __restrict__ Wx) {
    #pragma unroll
    for (int tt = 0; tt < 2; ++tt) {
      const int n = wid * 32 + 2 * l15 + tt;
      float w[8];
      #pragma unroll
      for (int j = 0; j < 8; ++j) {
        const int k = quad * 8 + j;
        w[j] = (k < CC) ? Wx[(size_t)n * CC + k] : 0.f;
      }
      split8(w, Xhi[tt], Xlo[tt]);
    }
  };
  auto loadBx = [&](const float* __restrict__ bx) {
    #pragma unroll
    for (int tt = 0; tt < 2; ++tt) bxr[tt] = bx[wid * 32 + 2 * l15 + tt];
  };

  // ---------------- init ----------------
  {
    unsigned* z;
    z = (unsigned*)&sm.hhi[0][0][0];
    for (int i = tid; i < NB * HS / 2; i += NTH) z[i] = 0u;
    z = (unsigned*)&sm.hlo[0][0][0];
    for (int i = tid; i < NB * HS / 2; i += NTH) z[i] = 0u;
    z = (unsigned*)&sm.xhi[0][0][0];
    for (int i = tid; i < 4 * NB * XS / 2; i += NTH) z[i] = 0u;
    z = (unsigned*)&sm.xlo[0][0][0];
    for (int i = tid; i < 4 * NB * XS / 2; i += NTH) z[i] = 0u;
  }
  loadWh(enc_Wh);
  loadWx(enc_Wx);
  loadBx(enc_bx);
  BAR();
  if (tid < NB * CC) {  // stage x_0 into slot 0
    const float v = x[(size_t)n0 * CC + tid];
    const _Float16 h = (_Float16)v;
    sm.xhi[0][tid / CC][tid % CC] = h;
    sm.xlo[0][tid / CC][tid % CC] = (_Float16)(v - (float)h);
  }
  BAR();

  // ---------------- encoder: 1 barrier/step, distance-2 prefetch ----------------
  auto encStep = [&](int t, auto IAc) {
    constexpr bool IA = decltype(IAc)::value;
    if (wid == 1) {  // issue x_{t+2} into set A (even t) / set B (odd t)
      const int tp = (t + 2 < TT) ? (t + 2) : (TT - 1);
      const float* xg = x + ((size_t)tp * NN + n0) * CC;
      if constexpr (IA) { pfA0 = xg[lane]; pfA1 = xg[lane + 64]; pfA2 = xg[lane + 128]; }
      else              { pfB0 = xg[lane]; pfB1 = xg[lane + 64]; pfB2 = xg[lane + 128]; }
    }
    const int rb = t & 1, wb = rb ^ 1, xs = t & 3;
    f32x4 aA0 = {0.f,0.f,0.f,0.f}, aA1 = {0.f,0.f,0.f,0.f};
    f32x4 aB0 = {0.f,0.f,0.f,0.f}, aB1 = {0.f,0.f,0.f,0.f};
    // x-term first: fills MFMA pipe while h reads stream in
    const half8 xh = *(const half8*)&sm.xhi[xs][l15][quad * 8];
    const half8 xl = *(const half8*)&sm.xlo[xs][l15][quad * 8];
    aA0 = MFMA(xh, Xhi[0], aA0, 0, 0, 0);
    aA1 = MFMA(xh, Xhi[1], aA1, 0, 0, 0);
    aB0 = MFMA(xl, Xhi[0], aB0, 0, 0, 0);
    aB1 = MFMA(xl, Xhi[1], aB1, 0, 0, 0);
    aB0 = MFMA(xh, Xlo[0], aB0, 0, 0, 0);
    aB1 = MFMA(xh, Xlo[1], aB1, 0, 0, 0);
    const _Float16* hh = &sm.hhi[rb][l15][0];
    const _Float16* hl = &sm.hlo[rb][l15][0];
    #pragma unroll
    for (int c = 0; c < 8; ++c) {
      const half8 ahi = *(const half8*)(hh + c * 32 + quad * 8);
      const half8 alo = *(const half8*)(hl + c * 32 + quad * 8);
      aA0 = MFMA(ahi, Whi[0][c], aA0, 0, 0, 0);
      aA1 = MFMA(ahi, Whi[1][c], aA1, 0, 0, 0);
      aB0 = MFMA(alo, Whi[0][c], aB0, 0, 0, 0);
      aB1 = MFMA(alo, Whi[1][c], aB1, 0, 0, 0);
      aA0 = MFMA(ahi, Wlo[0][c], aA0, 0, 0, 0);
      aA1 = MFMA(ahi, Wlo[1][c], aA1, 0, 0, 0);
    }
    const int colh = wid * 32 + 2 * l15;
    #pragma unroll
    for (int r = 0; r < 4; ++r) {
      const int m = quad * 4 + r;
      const float v0 = fmaxf(aA0[r] + aB0[r] + bxr[0], 0.f);
      const float v1 = fmaxf(aA1[r] + aB1[r] + bxr[1], 0.f);
      const _Float16 h0 = (_Float16)v0, h1 = (_Float16)v1;
      *(unsigned*)&sm.hhi[wb][m][colh] = pack2(h0, h1);
      *(unsigned*)&sm.hlo[wb][m][colh] =
          pack2((_Float16)(v0 - (float)h0), (_Float16)(v1 - (float)h1));
    }
    if (wid == 1) {  // write x_{t+1} (the OTHER set, issued one step ago)
      const int xw = (t + 1) & 3;
      float w0, w1, w2;
      if constexpr (IA) { w0 = pfB0; w1 = pfB1; w2 = pfB2; }
      else              { w0 = pfA0; w1 = pfA1; w2 = pfA2; }
      #pragma unroll
      for (int j = 0; j < 3; ++j) {
        const int i = lane + 64 * j;
        const float vv = (j == 0) ? w0 : (j == 1) ? w1 : w2;
        const _Float16 hx = (_Float16)vv;
        sm.xhi[xw][i / CC][i % CC] = hx;
        sm.xlo[xw][i / CC][i % CC] = (_Float16)(vv - (float)hx);
      }
    }
    BAR();
  };

  for (int t = 0; t < TT; t += 2) {
    encStep(t, TrueC{});
    encStep(t + 1, FalseC{});
  }
  // encoder final h now in planes[0]

  // ---------------- decoder setup ----------------
  loadWh(dec_Wh);
  loadWx(dec_Wx);
  loadBx(dec_bx);
  float by4[4];
  #pragma unroll
  for (int j = 0; j < 4; ++j) {
    const int o = quad * 4 + j;
    by4[j] = (o < KD) ? dec_by[o] : 0.f;
  }
  half8 wyh, wyl;  // dec_Wy B-fragment for THIS wave's k-chunk (registers)
  {
    float w[8];
    if (l15 < KD) {
      const float* p = dec_Wy + (size_t)l15 * DD + wid * 32 + quad * 8;
      *(float4*)&w[0] = *(const float4*)p;
      *(float4*)&w[4] = *(const float4*)(p + 4);
    } else {
      #pragma unroll
      for (int j = 0; j < 8; ++j) w[j] = 0.f;
    }
    split8(w, wyh, wyl);
  }
  // sos one-hot A-fragment in registers: column CC-2 = 10
  half8 aX;
  #pragma unroll
  for (int j = 0; j < 8; ++j)
    aX[j] = (_Float16)((quad * 8 + j == CC - 2) ? 1.f : 0.f);
  BAR();

  // ---------------- decoder: ONE barrier/step, no atomics ----------------
  for (int t = 0; t < TT; ++t) {
    const int rb = t & 1, wb = rb ^ 1, pb = t & 1;
    f32x4 aA0 = {0.f,0.f,0.f,0.f}, aA1 = {0.f,0.f,0.f,0.f};
    f32x4 aB0 = {0.f,0.f,0.f,0.f}, aB1 = {0.f,0.f,0.f,0.f};
    // x-term from in-register one-hot sos (exact in f16 -> no lo A plane)
    aA0 = MFMA(aX, Xhi[0], aA0, 0, 0, 0);
    aA1 = MFMA(aX, Xhi[1], aA1, 0, 0, 0);
    aB0 = MFMA(aX, Xlo[0], aB0, 0, 0, 0);
    aB1 = MFMA(aX, Xlo[1], aB1, 0, 0, 0);
    const _Float16* hh = &sm.hhi[rb][l15][0];
    const _Float16* hl = &sm.hlo[rb][l15][0];
    #pragma unroll
    for (int c = 0; c < 8; ++c) {
      const half8 ahi = *(const half8*)(hh + c * 32 + quad * 8);
      const half8 alo = *(const half8*)(hl + c * 32 + quad * 8);
      aA0 = MFMA(ahi, Whi[0][c], aA0, 0, 0, 0);
      aA1 = MFMA(ahi, Whi[1][c], aA1, 0, 0, 0);
      aB0 = MFMA(alo, Whi[0][c], aB0, 0, 0, 0);
      aB1 = MFMA(alo, Whi[1][c], aB1, 0, 0, 0);
      aA0 = MFMA(ahi, Wlo[0][c], aA0, 0, 0, 0);
      aA1 = MFMA(ahi, Wlo[1][c], aA1, 0, 0, 0);
    }
    const int colh = wid * 32 + 2 * l15;
    #pragma unroll
    for (int r = 0; r < 4; ++r) {
      const int m = quad * 4 + r;
      const float v0 = fmaxf(aA0[r] + aB0[r] + bxr[0], 0.f);
      const float v1 = fmaxf(aA1[r] + aB1[r] + bxr[1], 0.f);
      const _Float16 h0 = (_Float16)v0, h1 = (_Float16)v1;
      *(unsigned*)&sm.hhi[wb][m][colh] = pack2(h0, h1);
      *(unsigned*)&sm.hlo[wb][m][colh] =
          pack2((_Float16)(v0 - (float)h0), (_Float16)(v1 - (float)h1));
    }
    // y-partial from OWN just-written 32-col slice (no cross-wave dependency)
    asm volatile("s_waitcnt lgkmcnt(0)" ::: "memory");  // own writes -> readable
    const half8 yh8 = *(const half8*)&sm.hhi[wb][l15][wid * 32 + quad * 8];
    const half8 yl8 = *(const half8*)&sm.hlo[wb][l15][wid * 32 + quad * 8];
    f32x4 yp = {0.f,0.f,0.f,0.f};
    yp = MFMA(yh8, wyh, yp, 0, 0, 0);
    yp = MFMA(yl8, wyh, yp, 0, 0, 0);
    yp = MFMA(yh8, wyl, yp, 0, 0, 0);
    // publish partials: yp[r] = y-partial[row quad*4+r][class l15] from wave wid
    // write pattern: per r, banks 2 lanes/bank (free)
    #pragma unroll
    for (int r = 0; r < 4; ++r)
      sm.part2[pb][wid][quad * 4 + r][l15] = yp[r];
    BAR();  // h_t published + all 8 partials visible
    // every wave: reduce all 8 partials for (row=l15, classes quad*4..+3)
    f32x4 ys = *(const f32x4*)&sm.part2[pb][0][l15][quad * 4];
    #pragma unroll
    for (int w = 1; w < 8; ++w)
      ys += *(const f32x4*)&sm.part2[pb][w][l15][quad * 4];
    float yv[4];
    #pragma unroll
    for (int j = 0; j < 4; ++j) yv[j] = ys[j] + by4[j];
    if (wid == 0 && quad < 3) {  // single-writer out store, f32x4, fire-and-forget
      float4 st; st.x = yv[0]; st.y = yv[1]; st.z = yv[2]; st.w = yv[3];
      *(float4*)&out[((size_t)t * NN + n0 + l15) * KD + quad * 4] = st;
    }
    // in-lane argmax over this lane's 4 classes (ascending -> first-max kept)
    float v = -1e30f; int io = 0;
    #pragma unroll
    for (int j = 0; j < 4; ++j) {
      const int o = quad * 4 + j;
      const float cv = (o < KD) ? yv[j] : -1e30f;
      const bool take = cv > v;
      io = take ? o : io;
      v  = take ? cv : v;
    }
    // merge across the 4 quads (lane bits 4,5); np first-max tie-break.
    // every lane ends with argmax of ITS row l15 -> feeds aX directly.
    #pragma unroll
    for (int d = 16; d < 64; d <<= 1) {
      const float ov = __shfl_xor(v, d);
      const int   oi = __shfl_xor(io, d);
      const bool take = (ov > v) || (ov == v && oi < io);
      v  = take ? ov : v;
      io = take ? oi : io;
    }
    #pragma unroll
    for (int j = 0; j < 8; ++j)
      aX[j] = (_Float16)((quad * 8 + j == io) ? 1.f : 0.f);
  }
}

extern "C" void kernel_launch(void* const* d_in, const int* in_sizes, int n_in,
                              void* d_out, int out_size, void* d_ws, size_t ws_size,
                              hipStream_t stream) {
  (void)in_sizes; (void)n_in; (void)d_ws; (void)ws_size; (void)out_size;
  const float* x      = (const float*)d_in[0];
  const float* enc_Wx = (const float*)d_in[1];
  const float* enc_bx = (const float*)d_in[2];
  const float* enc_Wh = (const float*)d_in[3];
  // d_in[4] enc_Wy, d_in[5] enc_by: computed-but-discarded in the reference
  const float* dec_Wx = (const float*)d_in[6];
  const float* dec_bx = (const float*)d_in[7];
  const float* dec_Wh = (const float*)d_in[8];
  const float* dec_Wy = (const float*)d_in[9];
  const float* dec_by = (const float*)d_in[10];
  float* outp = (float*)d_out;

  seq2seq_kernel<<<NN / NB, NTH, 0, stream>>>(
      x, enc_Wx, enc_bx, enc_Wh, dec_Wx, dec_bx, dec_Wh, dec_Wy, dec_by, outp);
}

// Round 5
// 797.991 us; speedup vs baseline: 1.7485x; 1.0282x over previous
//
#include <hip/hip_runtime.h>
#include <cstdint>
#include <cstddef>

#define TT 256
#define NN 4096
#define CC 12
#define DD 256
#define KD 12
#define NB 16
#define NTH 512
#define HS 264   // halfs per h row: 256 + 8 pad (rows 16B-aligned)
#define XS 40    // halfs per x row: 32 + 8 pad
#define YS 20    // floats per part2 row: 16 + 4 pad (rows 16B-aligned)

typedef _Float16 half8 __attribute__((ext_vector_type(8)));
typedef __fp16 fp16x2 __attribute__((ext_vector_type(2)));
typedef float f32x4 __attribute__((ext_vector_type(4)));
#define MFMA __builtin_amdgcn_mfma_f32_16x16x32_f16

struct FalseC { static constexpr bool value = false; };
struct TrueC  { static constexpr bool value = true;  };

// LDS: 33,792 (h planes) + 10,240 (4 x slots) + 20,480 (part2 x2) = 64,512 B
struct alignas(16) SM {
  _Float16 hhi[2][NB][HS];    // h hi plane, double-buffered
  _Float16 hlo[2][NB][HS];    // h lo plane
  _Float16 xhi[4][NB][XS];    // x_t slots (4-deep, skewed prefetch)
  _Float16 xlo[4][NB][XS];
  float    part2[2][8][NB][YS];  // decoder y partials [buf][wave][row][class]
};

__device__ __forceinline__ void split8(const float* w, half8& hi, half8& lo) {
  #pragma unroll
  for (int j = 0; j < 8; ++j) {
    _Float16 h = (_Float16)w[j];
    hi[j] = h;
    lo[j] = (_Float16)(w[j] - (float)h);
  }
}

// packed hi/lo split: pkrtz(v0,v1) -> hi word; lo = v - f32(hi) -> lo word
__device__ __forceinline__ void packpair(float v0, float v1,
                                         unsigned& hw, unsigned& lw) {
  union { fp16x2 v; unsigned u; } a, b;
  a.v = __builtin_amdgcn_cvt_pkrtz(v0, v1);
  const float r0 = (float)a.v[0], r1 = (float)a.v[1];
  b.v = __builtin_amdgcn_cvt_pkrtz(v0 - r0, v1 - r1);
  hw = a.u; lw = b.u;
}

// Raw barrier, R1-proven form: drain LDS only (global ops stay in flight),
// builtin convergent s_barrier, sched_barrier pins order (rule #18).
__device__ __forceinline__ void BAR() {
  asm volatile("s_waitcnt lgkmcnt(0)" ::: "memory");
  __builtin_amdgcn_s_barrier();
  __builtin_amdgcn_sched_barrier(0);
}

__global__ __launch_bounds__(NTH, 2)
void seq2seq_kernel(const float* __restrict__ x,
                    const float* __restrict__ enc_Wx,
                    const float* __restrict__ enc_bx,
                    const float* __restrict__ enc_Wh,
                    const float* __restrict__ dec_Wx,
                    const float* __restrict__ dec_bx,
                    const float* __restrict__ dec_Wh,
                    const float* __restrict__ dec_Wy,
                    const float* __restrict__ dec_by,
                    float* __restrict__ out)
{
  __shared__ SM sm;
  const int tid  = (int)threadIdx.x;
  const int wid  = tid >> 6;
  const int lane = tid & 63;
  const int l15  = lane & 15;
  const int quad = lane >> 4;
  const int n0   = (int)blockIdx.x * NB;

  half8 Whi[2][8], Wlo[2][8];   // Wh B-fragments (reg-resident), persistent
  half8 Xhi[2], Xlo[2];         // Wx B-fragments (K=32 padded chunk)
  float bxr[2];
  // two prefetch register sets; body t issues x_{t+3}, body t+1 writes it
  float pfA0 = 0.f, pfA1 = 0.f, pfA2 = 0.f;
  float pfB0 = 0.f, pfB1 = 0.f, pfB2 = 0.f;
  // two accumulator sets: cur carries this step's x-term (pre-accumulated),
  // nxt receives next step's x-term pre-barrier.
  f32x4 accP[4], accQ[4];

  // B column mapping: n = wid*32 + 2*l15 + tt (lane's two outputs adjacent ->
  // packed b32 h-writes, 2 lanes/bank = free).
  auto loadWh = [&](const float* __restrict__ W) {
    #pragma unroll
    for (int tt = 0; tt < 2; ++tt) {
      const int n = wid * 32 + 2 * l15 + tt;
      #pragma unroll
      for (int c = 0; c < 8; ++c) {
        float w[8];
        const float* p = W + (size_t)n * DD + c * 32 + quad * 8;
        *(float4*)&w[0] = *(const float4*)p;
        *(float4*)&w[4] = *(const float4*)(p + 4);
        split8(w, Whi[tt][c], Wlo[tt][c]);
      }
    }
  };
  auto loadWx = [&](const float* __restrict__ Wx) {
    #pragma unroll
    for (int tt = 0; tt < 2; ++tt) {
      const int n = wid * 32 + 2 * l15 + tt;
      float w[8];
      #pragma unroll
      for (int j = 0; j < 8; ++j) {
        const int k = quad * 8 + j;
        w[j] = (k < CC) ? Wx[(size_t)n * CC + k] : 0.f;
      }
      split8(w, Xhi[tt], Xlo[tt]);
    }
  };
  auto loadBx = [&](const float* __restrict__ bx) {
    #pragma unroll
    for (int tt = 0; tt < 2; ++tt) bxr[tt] = bx[wid * 32 + 2 * l15 + tt];
  };

  // ---------------- init ----------------
  {
    unsigned* z;
    z = (unsigned*)&sm.hhi[0][0][0];
    for (int i = tid; i < NB * HS / 2; i += NTH) z[i] = 0u;
    z = (unsigned*)&sm.hlo[0][0][0];
    for (int i = tid; i < NB * HS / 2; i += NTH) z[i] = 0u;
    z = (unsigned*)&sm.xhi[0][0][0];
    for (int i = tid; i < 4 * NB * XS / 2; i += NTH) z[i] = 0u;
    z = (unsigned*)&sm.xlo[0][0][0];
    for (int i = tid; i < 4 * NB * XS / 2; i += NTH) z[i] = 0u;
  }
  loadWh(enc_Wh);
  loadWx(enc_Wx);
  loadBx(enc_bx);
  if (wid == 1) {  // pfB <- x_2 (body 0 stages it into slot 2)
    const float* xg = x + ((size_t)2 * NN + n0) * CC;
    pfB0 = xg[lane]; pfB1 = xg[lane + 64]; pfB2 = xg[lane + 128];
  }
  BAR();
  // direct-stage x_0 -> slot 0, x_1 -> slot 1
  #pragma unroll
  for (int s = 0; s < 2; ++s) {
    if (tid < NB * CC) {
      const float v = x[((size_t)s * NN + n0) * CC + tid];
      const _Float16 h = (_Float16)v;
      sm.xhi[s][tid / CC][tid % CC] = h;
      sm.xlo[s][tid / CC][tid % CC] = (_Float16)(v - (float)h);
    }
  }
  BAR();
  // x-term for step 0 into accP
  #pragma unroll
  for (int i = 0; i < 4; ++i) accP[i] = (f32x4){0.f, 0.f, 0.f, 0.f};
  {
    const half8 xh = *(const half8*)&sm.xhi[0][l15][quad * 8];
    const half8 xl = *(const half8*)&sm.xlo[0][l15][quad * 8];
    accP[0] = MFMA(xh, Xhi[0], accP[0], 0, 0, 0);
    accP[1] = MFMA(xh, Xhi[1], accP[1], 0, 0, 0);
    accP[2] = MFMA(xl, Xhi[0], accP[2], 0, 0, 0);
    accP[3] = MFMA(xl, Xhi[1], accP[3], 0, 0, 0);
    accP[2] = MFMA(xh, Xlo[0], accP[2], 0, 0, 0);
    accP[3] = MFMA(xh, Xlo[1], accP[3], 0, 0, 0);
  }

  // ---------------- encoder: skewed, 1 barrier/step ----------------
  // body t: h-MFMAs into cur (x-term already there); pre-barrier x-term for
  // t+1 into nxt; epilogue writes h_{t+1}; stage slot t+2; BAR.
  auto encCore = [&](int t, f32x4 (&cur)[4], f32x4 (&nxt)[4],
                     float pw0, float pw1, float pw2) {
    const int rb = t & 1, wb = rb ^ 1;
    const _Float16* hh = &sm.hhi[rb][l15][0];
    const _Float16* hl = &sm.hlo[rb][l15][0];
    #pragma unroll
    for (int c = 0; c < 8; ++c) {
      const half8 ahi = *(const half8*)(hh + c * 32 + quad * 8);
      const half8 alo = *(const half8*)(hl + c * 32 + quad * 8);
      cur[0] = MFMA(ahi, Whi[0][c], cur[0], 0, 0, 0);
      cur[1] = MFMA(ahi, Whi[1][c], cur[1], 0, 0, 0);
      cur[2] = MFMA(alo, Whi[0][c], cur[2], 0, 0, 0);
      cur[3] = MFMA(alo, Whi[1][c], cur[3], 0, 0, 0);
      cur[0] = MFMA(ahi, Wlo[0][c], cur[0], 0, 0, 0);
      cur[1] = MFMA(ahi, Wlo[1][c], cur[1], 0, 0, 0);
    }
    // next step's x-term (slot t+1 published >=1 barrier ago)
    #pragma unroll
    for (int i = 0; i < 4; ++i) nxt[i] = (f32x4){0.f, 0.f, 0.f, 0.f};
    if (t + 1 < TT) {
      const int xs = (t + 1) & 3;
      const half8 xh = *(const half8*)&sm.xhi[xs][l15][quad * 8];
      const half8 xl = *(const half8*)&sm.xlo[xs][l15][quad * 8];
      nxt[0] = MFMA(xh, Xhi[0], nxt[0], 0, 0, 0);
      nxt[1] = MFMA(xh, Xhi[1], nxt[1], 0, 0, 0);
      nxt[2] = MFMA(xl, Xhi[0], nxt[2], 0, 0, 0);
      nxt[3] = MFMA(xl, Xhi[1], nxt[3], 0, 0, 0);
      nxt[2] = MFMA(xh, Xlo[0], nxt[2], 0, 0, 0);
      nxt[3] = MFMA(xh, Xlo[1], nxt[3], 0, 0, 0);
    }
    // epilogue: merge + bias + relu + packed hi/lo split, write h_{t+1}
    const int colh = wid * 32 + 2 * l15;
    #pragma unroll
    for (int r = 0; r < 4; ++r) {
      const int m = quad * 4 + r;
      const float v0 = fmaxf(cur[0][r] + cur[2][r] + bxr[0], 0.f);
      const float v1 = fmaxf(cur[1][r] + cur[3][r] + bxr[1], 0.f);
      unsigned hw, lw;
      packpair(v0, v1, hw, lw);
      *(unsigned*)&sm.hhi[wb][m][colh] = hw;
      *(unsigned*)&sm.hlo[wb][m][colh] = lw;
    }
    // stage x_{t+2} into slot (t+2)&3 (regs issued one body ago)
    if (wid == 1) {
      const int xw = (t + 2) & 3;
      #pragma unroll
      for (int j = 0; j < 3; ++j) {
        const int i = lane + 64 * j;
        const float vv = (j == 0) ? pw0 : (j == 1) ? pw1 : pw2;
        const _Float16 hx = (_Float16)vv;
        sm.xhi[xw][i / CC][i % CC] = hx;
        sm.xlo[xw][i / CC][i % CC] = (_Float16)(vv - (float)hx);
      }
    }
    BAR();
  };

  auto encBody = [&](int t, auto IAc) {
    constexpr bool IA = decltype(IAc)::value;
    if (wid == 1) {  // issue pf regs for x_{t+3}
      const int tp = (t + 3 < TT) ? (t + 3) : (TT - 1);
      const float* xg = x + ((size_t)tp * NN + n0) * CC;
      if constexpr (IA) { pfA0 = xg[lane]; pfA1 = xg[lane + 64]; pfA2 = xg[lane + 128]; }
      else              { pfB0 = xg[lane]; pfB1 = xg[lane + 64]; pfB2 = xg[lane + 128]; }
    }
    if constexpr (IA) encCore(t, accP, accQ, pfB0, pfB1, pfB2);
    else              encCore(t, accQ, accP, pfA0, pfA1, pfA2);
  };

  for (int t = 0; t < TT; t += 2) {
    encBody(t, TrueC{});
    encBody(t + 1, FalseC{});
  }
  // encoder final h now in planes[0]

  // ---------------- decoder setup ----------------
  loadWh(dec_Wh);
  loadWx(dec_Wx);
  loadBx(dec_bx);
  float by4[4];
  #pragma unroll
  for (int j = 0; j < 4; ++j) {
    const int o = quad * 4 + j;
    by4[j] = (o < KD) ? dec_by[o] : 0.f;
  }
  half8 wyh, wyl;  // dec_Wy B-fragment for THIS wave's k-chunk (registers)
  {
    float w[8];
    if (l15 < KD) {
      const float* p = dec_Wy + (size_t)l15 * DD + wid * 32 + quad * 8;
      *(float4*)&w[0] = *(const float4*)p;
      *(float4*)&w[4] = *(const float4*)(p + 4);
    } else {
      #pragma unroll
      for (int j = 0; j < 8; ++j) w[j] = 0.f;
    }
    split8(w, wyh, wyl);
  }
  // sos one-hot A-fragment in registers: column CC-2 = 10
  half8 aX;
  #pragma unroll
  for (int j = 0; j < 8; ++j)
    aX[j] = (_Float16)((quad * 8 + j == CC - 2) ? 1.f : 0.f);
  BAR();

  // ---------------- decoder: ONE barrier/step, no atomics ----------------
  for (int t = 0; t < TT; ++t) {
    const int rb = t & 1, wb = rb ^ 1, pb = t & 1;
    f32x4 aA0 = {0.f,0.f,0.f,0.f}, aA1 = {0.f,0.f,0.f,0.f};
    f32x4 aB0 = {0.f,0.f,0.f,0.f}, aB1 = {0.f,0.f,0.f,0.f};
    // x-term from in-register one-hot sos (exact in f16 -> no lo A plane)
    aA0 = MFMA(aX, Xhi[0], aA0, 0, 0, 0);
    aA1 = MFMA(aX, Xhi[1], aA1, 0, 0, 0);
    aB0 = MFMA(aX, Xlo[0], aB0, 0, 0, 0);
    aB1 = MFMA(aX, Xlo[1], aB1, 0, 0, 0);
    const _Float16* hh = &sm.hhi[rb][l15][0];
    const _Float16* hl = &sm.hlo[rb][l15][0];
    #pragma unroll
    for (int c = 0; c < 8; ++c) {
      const half8 ahi = *(const half8*)(hh + c * 32 + quad * 8);
      const half8 alo = *(const half8*)(hl + c * 32 + quad * 8);
      aA0 = MFMA(ahi, Whi[0][c], aA0, 0, 0, 0);
      aA1 = MFMA(ahi, Whi[1][c], aA1, 0, 0, 0);
      aB0 = MFMA(alo, Whi[0][c], aB0, 0, 0, 0);
      aB1 = MFMA(alo, Whi[1][c], aB1, 0, 0, 0);
      aA0 = MFMA(ahi, Wlo[0][c], aA0, 0, 0, 0);
      aA1 = MFMA(ahi, Wlo[1][c], aA1, 0, 0, 0);
    }
    const int colh = wid * 32 + 2 * l15;
    #pragma unroll
    for (int r = 0; r < 4; ++r) {
      const int m = quad * 4 + r;
      const float v0 = fmaxf(aA0[r] + aB0[r] + bxr[0], 0.f);
      const float v1 = fmaxf(aA1[r] + aB1[r] + bxr[1], 0.f);
      unsigned hw, lw;
      packpair(v0, v1, hw, lw);
      *(unsigned*)&sm.hhi[wb][m][colh] = hw;
      *(unsigned*)&sm.hlo[wb][m][colh] = lw;
    }
    // y-partial from OWN just-written 32-col slice (no cross-wave dependency)
    asm volatile("s_waitcnt lgkmcnt(0)" ::: "memory");  // own writes -> readable
    const half8 yh8 = *(const half8*)&sm.hhi[wb][l15][wid * 32 + quad * 8];
    const half8 yl8 = *(const half8*)&sm.hlo[wb][l15][wid * 32 + quad * 8];
    f32x4 yp = {0.f,0.f,0.f,0.f};
    yp = MFMA(yh8, wyh, yp, 0, 0, 0);
    yp = MFMA(yl8, wyh, yp, 0, 0, 0);
    yp = MFMA(yh8, wyl, yp, 0, 0, 0);
    // publish partials: yp[r] = y-partial[row quad*4+r][class l15] from wave wid
    #pragma unroll
    for (int r = 0; r < 4; ++r)
      sm.part2[pb][wid][quad * 4 + r][l15] = yp[r];
    BAR();  // h_t published + all 8 partials visible
    // every wave: reduce all 8 partials for (row=l15, classes quad*4..+3)
    f32x4 ys = *(const f32x4*)&sm.part2[pb][0][l15][quad * 4];
    #pragma unroll
    for (int w = 1; w < 8; ++w)
      ys += *(const f32x4*)&sm.part2[pb][w][l15][quad * 4];
    float yv[4];
    #pragma unroll
    for (int j = 0; j < 4; ++j) yv[j] = ys[j] + by4[j];
    if (wid == 0 && quad < 3) {  // single-writer out store, f32x4, fire-and-forget
      float4 st; st.x = yv[0]; st.y = yv[1]; st.z = yv[2]; st.w = yv[3];
      *(float4*)&out[((size_t)t * NN + n0 + l15) * KD + quad * 4] = st;
    }
    // in-lane argmax over this lane's 4 classes (ascending -> first-max kept)
    float v = -1e30f; int io = 0;
    #pragma unroll
    for (int j = 0; j < 4; ++j) {
      const int o = quad * 4 + j;
      const float cv = (o < KD) ? yv[j] : -1e30f;
      const bool take = cv > v;
      io = take ? o : io;
      v  = take ? cv : v;
    }
    // merge across the 4 quads (lane bits 4,5); np first-max tie-break.
    #pragma unroll
    for (int d = 16; d < 64; d <<= 1) {
      const float ov = __shfl_xor(v, d);
      const int   oi = __shfl_xor(io, d);
      const bool take = (ov > v) || (ov == v && oi < io);
      v  = take ? ov : v;
      io = take ? oi : io;
    }
    // io = argmax for row l15, present in every lane -> rebuild one-hot A frag
    #pragma unroll
    for (int j = 0; j < 8; ++j)
      aX[j] = (_Float16)((quad * 8 + j == io) ? 1.f : 0.f);
  }
}

extern "C" void kernel_launch(void* const* d_in, const int* in_sizes, int n_in,
                              void* d_out, int out_size, void* d_ws, size_t ws_size,
                              hipStream_t stream) {
  (void)in_sizes; (void)n_in; (void)d_ws; (void)ws_size; (void)out_size;
  const float* x      = (const float*)d_in[0];
  const float* enc_Wx = (const float*)d_in[1];
  const float* enc_bx = (const float*)d_in[2];
  const float* enc_Wh = (const float*)d_in[3];
  // d_in[4] enc_Wy, d_in[5] enc_by: computed-but-discarded in the reference
  const float* dec_Wx = (const float*)d_in[6];
  const float* dec_bx = (const float*)d_in[7];
  const float* dec_Wh = (const float*)d_in[8];
  const float* dec_Wy = (const float*)d_in[9];
  const float* dec_by = (const float*)d_in[10];
  float* outp = (float*)d_out;

  seq2seq_kernel<<<NN / NB, NTH, 0, stream>>>(
      x, enc_Wx, enc_bx, enc_Wh, dec_Wx, dec_bx, dec_Wh, dec_Wy, dec_by, outp);
}